// Round 11
// baseline (856.832 us; speedup 1.0000x reference)
//
#include <hip/hip_runtime.h>
#include <hip/hip_bf16.h>

#define DEVFN __device__ __forceinline__

typedef __attribute__((ext_vector_type(8))) short bf16x8;
typedef __attribute__((ext_vector_type(4))) float f32x4;

constexpr int T = 128, C = 8, K = 9;
constexpr int HW = 1024;   // 32x32
constexpr int BT = 512;    // B*T images
constexpr size_t Z_SIZE = (size_t)BT * C * HW;

constexpr int SROW64 = 34 * 128;      // 4352 B per 64-ch site-row
constexpr int HT_B = 12 * SROW64;     // 52224  (h tile: rows R0-2..R0+9)
constexpr int UT_B = 6 * SROW64;      // 26112  (u ring: 6 slots)
constexpr int TILE64 = 10 * SROW64;   // conv_final tile
constexpr int SROW32 = 34 * 64;
constexpr int TILE32 = 10 * SROW32;   // conv_in tile

// fragment-packed weights (bf16 element offsets): [tap][c][mt][lane][8]
constexpr int WP_IN = 0;
constexpr int WP_W1_0 = 18432;
constexpr int WP_W2_0 = 55296;
constexpr int WP_W1_1 = 92160;
constexpr int WP_W2_1 = 129024;
constexpr int WP_OUT = 165888;
constexpr int WP_TOT = 175104;

DEVFN ushort f2bs(float x) {
  __hip_bfloat16 h = __float2bfloat16(x);
  ushort u;
  __builtin_memcpy(&u, &h, 2);
  return u;
}
DEVFN float bs2f(ushort u) {
  __hip_bfloat16 h;
  __builtin_memcpy(&h, &u, 2);
  return __bfloat162float(h);
}

DEVFN void interp_params(const int* __restrict__ idx, int b, int t,
                         int& t0, int& t1, float& ar, float& a) {
  const int* ib = idx + b * K;
  int cnt = 0;
#pragma unroll
  for (int k = 0; k < K; ++k) cnt += (ib[k] <= t) ? 1 : 0;
  int seg = min(max(cnt - 1, 0), K - 2);
  t0 = ib[seg];
  t1 = ib[seg + 1];
  ar = (float)(t - t0) / (float)max(t1 - t0, 1);
  a = fminf(fmaxf(ar, 0.f), 1.f);
}

// ---------------------------------------------------------------------------
__global__ __launch_bounds__(256) void pack_weights(
    const float* __restrict__ w_in, const float* __restrict__ w1s,
    const float* __restrict__ w2s, const float* __restrict__ w_out,
    __hip_bfloat16* __restrict__ wp) {
  int e = blockIdx.x * 256 + threadIdx.x;
  if (e >= WP_TOT) return;
  float v;
  if (e < WP_W1_0) {
    int tap = e / 2048;
    int r2 = e % 2048;
    int mt = r2 / 512;
    int lane = (r2 / 8) & 63;
    int el = e & 7;
    int oc = mt * 16 + (lane & 15);
    int ic = (lane >> 4) * 8 + el;
    v = (ic < 25) ? w_in[((size_t)oc * 25 + ic) * 9 + tap] : 0.f;
  } else if (e < WP_OUT) {
    int r = e - WP_W1_0;
    int layer = r / 36864;  // 0:w1b0 1:w2b0 2:w1b1 3:w2b1
    int r2 = r % 36864;
    int tap = r2 / 4096;
    int c = (r2 / 2048) & 1;
    int mt = (r2 / 512) & 3;
    int lane = (r2 / 8) & 63;
    int el = r2 & 7;
    int oc = mt * 16 + (lane & 15);
    int ic = c * 32 + (lane >> 4) * 8 + el;
    const float* src = (layer & 1) ? w2s : w1s;
    int blk = layer >> 1;
    v = src[(((size_t)blk * 64 + oc) * 64 + ic) * 9 + tap];
  } else {
    int r2 = e - WP_OUT;
    int tap = r2 / 1024;
    int c = (r2 / 512) & 1;
    int lane = (r2 / 8) & 63;
    int el = r2 & 7;
    int oc = lane & 15;
    int ic = c * 32 + (lane >> 4) * 8 + el;
    v = (oc < 9) ? w_out[((size_t)oc * 64 + ic) * 9 + tap] : 0.f;
  }
  wp[e] = __float2bfloat16(v);
}

// ---------------------------------------------------------------------------
// fused residual block: out = in + conv2(silu(conv1(in)+b1)) + b2.
// grid (BT, 4) 8-row strips; 512 thr (8 waves); LDS = hT(12 rows)+u-ring(6).
// Phase ledger (every phase is read-only or write-only per region):
//  S : write hT (stage), write uT halo cols (zero once)      | B1
//  C1a: read hT -> write uT slots 0..5 (interior)            | B2
//  C2a: read uT 0..5 + hT -> acc2 in REGISTERS (no writes)   | B3
//  W2a: write uT slots 0..3 (scratch)                        | B4
//  Sta: read uT 0..3 -> global store rows R0..R0+3           | B5
//  C1b: read hT -> write uT slots 0..3 (u rows 6..9)         | B6
//  C2b: read uT 0..5 + hT -> acc2 regs                       | B7
//  W2b: write uT slots 0..3                                  | B8
//  Stb: read uT 0..3 -> global store rows R0+4..R0+7
// ---------------------------------------------------------------------------
__global__ __launch_bounds__(512) void fused_rb(
    const __hip_bfloat16* __restrict__ in,   // h  [512][1024][64]
    const __hip_bfloat16* __restrict__ wp1,  // [9][2][4][64][8]
    const __hip_bfloat16* __restrict__ wp2,
    const float* __restrict__ b1, const float* __restrict__ b2,
    __hip_bfloat16* __restrict__ out) {      // h_new
  __shared__ __align__(16) char sBuf[HT_B + UT_B];  // 78336 B -> 2 blocks/CU
  char* hT = sBuf;
  char* uT = sBuf + HT_B;

  const int img = blockIdx.x;
  const int R0 = blockIdx.y * 8;
  const int tid = threadIdx.x;
  const int lane = tid & 63, wv = tid >> 6, g = lane >> 4, ln = lane & 15;
  const size_t imgBase = (size_t)img * HW * 64;

  // swizzled read bases: + row*4352 + xh*2048 at use
  int base[3][2];
#pragma unroll
  for (int d = 0; d < 3; ++d)
#pragma unroll
    for (int c = 0; c < 2; ++c)
      base[d][c] = (((ln + d) * 128 + c * 64 + g * 16) ^ (((ln + d) & 7) << 4));
  // write-granule base (site sx = 1 + ln, + xh*2048 at use)
  const int wkey = ((ln + 1) & 7) << 4;
  int wbase[4];
#pragma unroll
  for (int mt = 0; mt < 4; ++mt)
    wbase[mt] = (ln + 1) * 128 + ((mt * 32 + g * 8) ^ wkey);

  // ---- S: stage h rows R0-2..R0+9 (zero outside image) ----
  for (int e = tid; e < 3264; e += 512) {
    int srow = e / 272;
    int rem = e - srow * 272;
    int sx = rem >> 3, slot = rem & 7;
    int gy = R0 - 2 + srow, gx = sx - 1;
    int4 v = int4{0, 0, 0, 0};
    if (((unsigned)gy < 32u) & ((unsigned)gx < 32u))
      v = *(const int4*)(in + imgBase + (size_t)(gy * 32 + gx) * 64 + slot * 8);
    int dst = (srow * 34 + sx) * 128 + ((slot * 16) ^ ((sx & 7) << 4));
    *(int4*)(hT + dst) = v;
  }
  // zero u-ring halo columns (sites 0 and 33 of all 6 slots) ONCE; these are
  // never written elsewhere (conv1/scratch write sites 1..32 only).
  if (tid < 96) {
    int slot = tid >> 4, rem = tid & 15;
    int site = (rem >> 3) ? 33 : 0, q = rem & 7;
    *(int4*)(uT + slot * SROW64 + site * 128 + q * 16) = int4{0, 0, 0, 0};
  }
  __syncthreads();  // B1

  // ---- conv1 unit: u[ur] (abs row R0-1+ur) from hT rows ur..ur+2 ----
  auto conv1_unit = [&](int ur, int xh) {
    const int slot = (ur < 6) ? ur : ur - 6;
    const int aro = R0 - 1 + ur;
    if ((unsigned)aro < 32u) {
      f32x4 acc[4];
#pragma unroll
      for (int mt = 0; mt < 4; ++mt) acc[mt] = (f32x4)0.f;
#pragma unroll
      for (int c = 0; c < 2; ++c)
#pragma unroll
        for (int d = 0; d < 3; ++d) {
          bf16x8 bv[3];
#pragma unroll
          for (int dyi = 0; dyi < 3; ++dyi)
            bv[dyi] = *(const bf16x8*)(hT + (ur + dyi) * SROW64 + base[d][c] +
                                       xh * 2048);
#pragma unroll
          for (int mt = 0; mt < 4; ++mt)
#pragma unroll
            for (int dyi = 0; dyi < 3; ++dyi) {
              bf16x8 av = *(const bf16x8*)(wp1 +
                                           ((((dyi * 3 + d) * 2 + c) * 4 + mt) *
                                                64 +
                                            lane) *
                                               8);
              acc[mt] = __builtin_amdgcn_mfma_f32_16x16x32_bf16(
                  av, bv[dyi], acc[mt], 0, 0, 0);
            }
        }
#pragma unroll
      for (int mt = 0; mt < 4; ++mt) {
        const float4 bv4 = *(const float4*)(b1 + mt * 16 + g * 4);
        float v0 = acc[mt][0] + bv4.x;
        float v1 = acc[mt][1] + bv4.y;
        float v2 = acc[mt][2] + bv4.z;
        float v3 = acc[mt][3] + bv4.w;
        ushort4 s;
        s.x = f2bs(v0 / (1.f + expf(-v0)));
        s.y = f2bs(v1 / (1.f + expf(-v1)));
        s.z = f2bs(v2 / (1.f + expf(-v2)));
        s.w = f2bs(v3 / (1.f + expf(-v3)));
        *(ushort4*)(uT + slot * SROW64 + xh * 2048 + wbase[mt]) = s;
      }
    } else {
      ushort4 z = ushort4{0, 0, 0, 0};
#pragma unroll
      for (int mt = 0; mt < 4; ++mt)
        *(ushort4*)(uT + slot * SROW64 + xh * 2048 + wbase[mt]) = z;
    }
  };

  // ---- conv2 compute (NO LDS writes): resid init from hT, taps from uT ----
  auto conv2_compute = [&](int orow, int xh, f32x4 (&acc)[4]) {
    const int hr = orow + 2;
#pragma unroll
    for (int mt = 0; mt < 4; ++mt) {
      ushort4 h4 = *(const ushort4*)(hT + hr * SROW64 + xh * 2048 + wbase[mt]);
      f32x4 a4;
      a4[0] = bs2f(h4.x);
      a4[1] = bs2f(h4.y);
      a4[2] = bs2f(h4.z);
      a4[3] = bs2f(h4.w);
      acc[mt] = a4;
    }
#pragma unroll
    for (int c = 0; c < 2; ++c)
#pragma unroll
      for (int d = 0; d < 3; ++d) {
        bf16x8 bv[3];
#pragma unroll
        for (int dyi = 0; dyi < 3; ++dyi) {
          int ur = orow + dyi;
          int slot = (ur < 6) ? ur : ur - 6;
          bv[dyi] =
              *(const bf16x8*)(uT + slot * SROW64 + base[d][c] + xh * 2048);
        }
#pragma unroll
        for (int mt = 0; mt < 4; ++mt)
#pragma unroll
          for (int dyi = 0; dyi < 3; ++dyi) {
            bf16x8 av = *(const bf16x8*)(wp2 +
                                         ((((dyi * 3 + d) * 2 + c) * 4 + mt) *
                                              64 +
                                          lane) *
                                             8);
            acc[mt] = __builtin_amdgcn_mfma_f32_16x16x32_bf16(av, bv[dyi],
                                                              acc[mt], 0, 0, 0);
          }
      }
  };

  // ---- scratch write (after barrier): +b2, bf16, into uT slots 0..3 ----
  auto scratch_write = [&](const f32x4 (&acc)[4], int sslot, int xh) {
#pragma unroll
    for (int mt = 0; mt < 4; ++mt) {
      const float4 bv4 = *(const float4*)(b2 + mt * 16 + g * 4);
      ushort4 s;
      s.x = f2bs(acc[mt][0] + bv4.x);
      s.y = f2bs(acc[mt][1] + bv4.y);
      s.z = f2bs(acc[mt][2] + bv4.z);
      s.w = f2bs(acc[mt][3] + bv4.w);
      *(ushort4*)(uT + sslot * SROW64 + xh * 2048 + wbase[mt]) = s;
    }
  };

  // ---- coalesced store of 4 rows from scratch slots 0..3 ----
  auto store_chunk = [&](int ch) {
    const int row = tid >> 7;           // 0..3
    const int px = (tid >> 2) & 31;
    const int q = tid & 3;
    const int sx = px + 1;
    const int key = (sx & 7) << 4;
    const char* sp = uT + row * SROW64 + sx * 128;
    int4 v0 = *(const int4*)(sp + ((q * 32) ^ key));
    int4 v1 = *(const int4*)(sp + ((q * 32 + 16) ^ key));
    const int grow = R0 + ch * 4 + row;
    char* op = (char*)(out + imgBase + (size_t)(grow * 32 + px) * 64) + q * 32;
    *(int4*)op = v0;
    *(int4*)(op + 16) = v1;
  };

  f32x4 acc2[4];

  // ---- chunk 1: u rows 0..5 (12 units), out rows R0..R0+3 ----
  conv1_unit(wv >> 1, wv & 1);
  if (wv < 4) conv1_unit(4 + (wv >> 1), wv & 1);
  __syncthreads();  // B2
  conv2_compute(wv >> 1, wv & 1, acc2);
  __syncthreads();  // B3
  scratch_write(acc2, (wv >> 1), wv & 1);
  __syncthreads();  // B4
  store_chunk(0);
  __syncthreads();  // B5

  // ---- chunk 2: u rows 6..9 -> slots 0..3, out rows R0+4..R0+7 ----
  conv1_unit(6 + (wv >> 1), wv & 1);
  __syncthreads();  // B6
  conv2_compute(4 + (wv >> 1), wv & 1, acc2);
  __syncthreads();  // B7
  scratch_write(acc2, (wv >> 1), wv & 1);
  __syncthreads();  // B8
  store_chunk(1);
}

// ---------------------------------------------------------------------------
// conv_in: prep fused into staging. grid (BT,4), 256 thr.
// ---------------------------------------------------------------------------
__global__ __launch_bounds__(256) void conv_in_t(
    const float* __restrict__ latents, const int* __restrict__ idx,
    const __hip_bfloat16* __restrict__ wpf, const float* __restrict__ bias,
    __hip_bfloat16* __restrict__ out) {
  __shared__ __align__(16) char sBuf[TILE32];

  const int img = blockIdx.x;
  const int R0 = blockIdx.y * 8;
  const int tid = threadIdx.x;
  const int lane = tid & 63, wv = tid >> 6, g = lane >> 4, ln = lane & 15;
  const int r0L = wv * 2;
  const int b = img >> 7, t = img & 127;

  int t0, t1;
  float ar, a;
  interp_params(idx, b, t, t0, t1, ar, a);
  const float* z0p = latents + ((size_t)b * T + t0) * C * HW;
  const float* z1p = latents + ((size_t)b * T + t1) * C * HW;
  const ushort ab = f2bs(a);

  for (int e = tid; e < 340; e += 256) {
    int srow = e / 34, sx = e - srow * 34;
    int gy = R0 - 1 + srow, gx = sx - 1;
    char* sp = sBuf + srow * SROW32 + sx * 64;
    const int key = (sx & 3) << 4;
    if (((unsigned)gy < 32u) & ((unsigned)gx < 32u)) {
      int p = gy * 32 + gx;
      float v0[8], v1[8];
#pragma unroll
      for (int c2 = 0; c2 < 8; ++c2) {
        v0[c2] = z0p[c2 * HW + p];
        v1[c2] = z1p[c2 * HW + p];
      }
      ushort u[8];
      int4 q;
#pragma unroll
      for (int c2 = 0; c2 < 8; ++c2) u[c2] = f2bs((1.f - a) * v0[c2] + a * v1[c2]);
      q.x = (int)u[0] | ((int)u[1] << 16); q.y = (int)u[2] | ((int)u[3] << 16);
      q.z = (int)u[4] | ((int)u[5] << 16); q.w = (int)u[6] | ((int)u[7] << 16);
      *(int4*)(sp + (0 ^ key)) = q;
#pragma unroll
      for (int c2 = 0; c2 < 8; ++c2) u[c2] = f2bs(v0[c2]);
      q.x = (int)u[0] | ((int)u[1] << 16); q.y = (int)u[2] | ((int)u[3] << 16);
      q.z = (int)u[4] | ((int)u[5] << 16); q.w = (int)u[6] | ((int)u[7] << 16);
      *(int4*)(sp + (16 ^ key)) = q;
#pragma unroll
      for (int c2 = 0; c2 < 8; ++c2) u[c2] = f2bs(v1[c2]);
      q.x = (int)u[0] | ((int)u[1] << 16); q.y = (int)u[2] | ((int)u[3] << 16);
      q.z = (int)u[4] | ((int)u[5] << 16); q.w = (int)u[6] | ((int)u[7] << 16);
      *(int4*)(sp + (32 ^ key)) = q;
      q.x = (int)ab; q.y = 0; q.z = 0; q.w = 0;
      *(int4*)(sp + (48 ^ key)) = q;
    } else {
      int4 z = int4{0, 0, 0, 0};
#pragma unroll
      for (int sl = 0; sl < 4; ++sl) *(int4*)(sp + ((sl * 16) ^ key)) = z;
    }
  }
  __syncthreads();

  int base[3];
#pragma unroll
  for (int d = 0; d < 3; ++d)
    base[d] = r0L * SROW32 + (((ln + d) * 64 + g * 16) ^ (((ln + d) & 3) << 4));

  f32x4 acc[4][4];
#pragma unroll
  for (int mt = 0; mt < 4; ++mt)
#pragma unroll
    for (int nt = 0; nt < 4; ++nt) acc[mt][nt] = (f32x4)0.f;

#pragma unroll
  for (int d = 0; d < 3; ++d) {
    bf16x8 bv[4][2];
#pragma unroll
    for (int j = 0; j < 4; ++j)
#pragma unroll
      for (int xh = 0; xh < 2; ++xh)
        bv[j][xh] = *(const bf16x8*)(sBuf + base[d] + xh * 1024 + j * SROW32);
#pragma unroll
    for (int mt = 0; mt < 4; ++mt)
#pragma unroll
      for (int dyi = 0; dyi < 3; ++dyi) {
        const int tap = dyi * 3 + d;
        bf16x8 av = *(const bf16x8*)(wpf + ((tap * 4 + mt) * 64 + lane) * 8);
#pragma unroll
        for (int oy = 0; oy < 2; ++oy)
#pragma unroll
          for (int xh = 0; xh < 2; ++xh)
            acc[mt][oy * 2 + xh] = __builtin_amdgcn_mfma_f32_16x16x32_bf16(
                av, bv[oy + dyi][xh], acc[mt][oy * 2 + xh], 0, 0, 0);
      }
  }

  const size_t imgBase = (size_t)img * HW * 64;
#pragma unroll
  for (int mt = 0; mt < 4; ++mt) {
    const float4 bv4 = *(const float4*)(bias + mt * 16 + g * 4);
#pragma unroll
    for (int nt = 0; nt < 4; ++nt) {
      const int px = (R0 + r0L + (nt >> 1)) * 32 + (nt & 1) * 16 + ln;
      float v0 = acc[mt][nt][0] + bv4.x;
      float v1 = acc[mt][nt][1] + bv4.y;
      float v2 = acc[mt][nt][2] + bv4.z;
      float v3 = acc[mt][nt][3] + bv4.w;
      ushort4 sv;
      sv.x = f2bs(v0 / (1.f + expf(-v0)));
      sv.y = f2bs(v1 / (1.f + expf(-v1)));
      sv.z = f2bs(v2 / (1.f + expf(-v2)));
      sv.w = f2bs(v3 / (1.f + expf(-v3)));
      *(ushort4*)(out + imgBase + (size_t)px * 64 + mt * 16 + g * 4) = sv;
    }
  }
}

// ---------------------------------------------------------------------------
// final conv (64->16, 9 real) fused with z_hat / conf epilogue.
// ---------------------------------------------------------------------------
__global__ __launch_bounds__(256) void conv_final_t(
    const __hip_bfloat16* __restrict__ in, const __hip_bfloat16* __restrict__ wpf,
    const float* __restrict__ bias, const float* __restrict__ latents,
    const int* __restrict__ idx, float* __restrict__ dout) {
  __shared__ __align__(16) char sBuf[TILE64];
  __shared__ float sOut[256][17];

  const int img = blockIdx.x;
  const int R0 = blockIdx.y * 8;
  const int tid = threadIdx.x;
  const int lane = tid & 63, wv = tid >> 6, g = lane >> 4, ln = lane & 15;
  const int r0L = wv * 2;
  const int b = img >> 7, t = img & 127;
  const size_t imgBase = (size_t)img * HW * 64;

  int t0, t1;
  float ar, a;
  interp_params(idx, b, t, t0, t1, ar, a);
  const float* z0p = latents + ((size_t)b * T + t0) * C * HW;
  const float* z1p = latents + ((size_t)b * T + t1) * C * HW;

  for (int e = tid; e < 2720; e += 256) {
    int srow = e / 272;
    int rem = e - srow * 272;
    int sx = rem >> 3, slot = rem & 7;
    int gy = R0 - 1 + srow, gx = sx - 1;
    int4 v = int4{0, 0, 0, 0};
    if (((unsigned)gy < 32u) & ((unsigned)gx < 32u))
      v = *(const int4*)(in + imgBase + (size_t)(gy * 32 + gx) * 64 + slot * 8);
    int dst = (srow * 34 + sx) * 128 + ((slot * 16) ^ ((sx & 7) << 4));
    *(int4*)(sBuf + dst) = v;
  }
  __syncthreads();

  int base[3][2];
#pragma unroll
  for (int d = 0; d < 3; ++d)
#pragma unroll
    for (int c = 0; c < 2; ++c)
      base[d][c] = r0L * SROW64 +
                   (((ln + d) * 128 + c * 64 + g * 16) ^ (((ln + d) & 7) << 4));

  f32x4 acc[4];
#pragma unroll
  for (int nt = 0; nt < 4; ++nt) acc[nt] = (f32x4)0.f;

#pragma unroll
  for (int c = 0; c < 2; ++c)
#pragma unroll
    for (int d = 0; d < 3; ++d) {
      bf16x8 bv[4][2];
#pragma unroll
      for (int j = 0; j < 4; ++j)
#pragma unroll
        for (int xh = 0; xh < 2; ++xh)
          bv[j][xh] =
              *(const bf16x8*)(sBuf + base[d][c] + xh * 2048 + j * SROW64);
#pragma unroll
      for (int dyi = 0; dyi < 3; ++dyi) {
        const int tap = dyi * 3 + d;
        bf16x8 av = *(const bf16x8*)(wpf + ((tap * 2 + c) * 64 + lane) * 8);
#pragma unroll
        for (int oy = 0; oy < 2; ++oy)
#pragma unroll
          for (int xh = 0; xh < 2; ++xh)
            acc[oy * 2 + xh] = __builtin_amdgcn_mfma_f32_16x16x32_bf16(
                av, bv[oy + dyi][xh], acc[oy * 2 + xh], 0, 0, 0);
      }
    }

#pragma unroll
  for (int nt = 0; nt < 4; ++nt) {
    const int pxl = (r0L + (nt >> 1)) * 32 + (nt & 1) * 16 + ln;
#pragma unroll
    for (int r = 0; r < 4; ++r) {
      const int oc = g * 4 + r;
      sOut[pxl][oc] = acc[nt][r] + ((oc < 9) ? bias[oc] : 0.f);
    }
  }
  __syncthreads();

  const bool interior = (ar > 0.f) && (ar < 1.f);
  const float aa = a * (1.f - a);
  const int px = R0 * 32 + tid;
#pragma unroll
  for (int c2 = 0; c2 < 8; ++c2) {
    float res = sOut[tid][c2];
    float v0 = z0p[c2 * HW + px], v1 = z1p[c2 * HW + px];
    float zb = (1.f - a) * v0 + a * v1;
    dout[((size_t)img * C + c2) * HW + px] = zb + aa * res;
  }
  float unc = 1.f / (1.f + expf(-sOut[tid][8]));
  float conf = interior ? fminf(fmaxf(1.f - unc, 0.f), 1.f) : 1.f;
  dout[Z_SIZE + (size_t)img * HW + px] = conf;
}

// ---------------------------------------------------------------------------
extern "C" void kernel_launch(void* const* d_in, const int* in_sizes, int n_in,
                              void* d_out, int out_size, void* d_ws,
                              size_t ws_size, hipStream_t stream) {
  const float* latents = (const float*)d_in[0];
  const int* idx = (const int*)d_in[1];
  const float* w_in = (const float*)d_in[2];
  const float* b_in = (const float*)d_in[3];
  const float* w1s = (const float*)d_in[4];
  const float* b1s = (const float*)d_in[5];
  const float* w2s = (const float*)d_in[6];
  const float* b2s = (const float*)d_in[7];
  const float* w_out = (const float*)d_in[8];
  const float* b_out = (const float*)d_in[9];
  float* dout = (float*)d_out;

  char* ws = (char*)d_ws;
  __hip_bfloat16* A = (__hip_bfloat16*)ws;                        // 64 MiB
  __hip_bfloat16* Bb = (__hip_bfloat16*)(ws + (size_t)67108864);  // 64 MiB
  __hip_bfloat16* wpk = (__hip_bfloat16*)(ws + (size_t)134217728);

  pack_weights<<<(WP_TOT + 255) / 256, 256, 0, stream>>>(w_in, w1s, w2s, w_out,
                                                         wpk);

  conv_in_t<<<dim3(BT, 4), 256, 0, stream>>>(latents, idx, wpk + WP_IN, b_in,
                                             A);

  fused_rb<<<dim3(BT, 4), 512, 0, stream>>>(A, wpk + WP_W1_0, wpk + WP_W2_0,
                                            b1s, b2s, Bb);
  fused_rb<<<dim3(BT, 4), 512, 0, stream>>>(Bb, wpk + WP_W1_1, wpk + WP_W2_1,
                                            b1s + 64, b2s + 64, A);

  conv_final_t<<<dim3(BT, 4), 256, 0, stream>>>(A, wpk + WP_OUT, b_out, latents,
                                                idx, dout);
}

// Round 12
// 514.871 us; speedup vs baseline: 1.6642x; 1.6642x over previous
//
#include <hip/hip_runtime.h>
#include <hip/hip_bf16.h>

#define DEVFN __device__ __forceinline__

typedef __attribute__((ext_vector_type(8))) short bf16x8;
typedef __attribute__((ext_vector_type(4))) float f32x4;

constexpr int T = 128, C = 8, K = 9;
constexpr int HW = 1024;   // 32x32
constexpr int BT = 512;    // B*T images
constexpr size_t Z_SIZE = (size_t)BT * C * HW;

constexpr int SR = 34 * 128;  // 4352 B per site-row (34 sites x 128 B)

// fragment-packed weights (bf16 element offsets): [tap][c][mt][lane][8]
constexpr int WP_IN = 0;        // conv_in  [9][1][4][64][8]
constexpr int WP_W1_0 = 18432;  // then w1b0,w2b0,w1b1,w2b1 each 36864
constexpr int WP_OUT = 165888;  // final [9][2][1][64][8]
constexpr int WP_TOT = 175104;

DEVFN ushort f2bs(float x) {
  __hip_bfloat16 h = __float2bfloat16(x);
  ushort u;
  __builtin_memcpy(&u, &h, 2);
  return u;
}
DEVFN float bs2f(ushort u) {
  __hip_bfloat16 h;
  __builtin_memcpy(&h, &u, 2);
  return __bfloat162float(h);
}

// idx rows sorted ascending; branchless count, no local array (rule #20).
DEVFN void interp_params(const int* __restrict__ idx, int b, int t,
                         int& t0, int& t1, float& ar, float& a) {
  const int* ib = idx + b * K;
  int cnt = 0;
#pragma unroll
  for (int k = 0; k < K; ++k) cnt += (ib[k] <= t) ? 1 : 0;
  int seg = min(max(cnt - 1, 0), K - 2);
  t0 = ib[seg];
  t1 = ib[seg + 1];
  ar = (float)(t - t0) / (float)max(t1 - t0, 1);
  a = fminf(fmaxf(ar, 0.f), 1.f);
}

// ---------------------------------------------------------------------------
__global__ __launch_bounds__(256) void pack_weights(
    const float* __restrict__ w_in, const float* __restrict__ w1s,
    const float* __restrict__ w2s, const float* __restrict__ w_out,
    __hip_bfloat16* __restrict__ wp) {
  int e = blockIdx.x * 256 + threadIdx.x;
  if (e >= WP_TOT) return;
  float v;
  if (e < WP_W1_0) {
    int tap = e / 2048;
    int r2 = e % 2048;
    int mt = r2 / 512;
    int lane = (r2 / 8) & 63;
    int el = e & 7;
    int oc = mt * 16 + (lane & 15);
    int ic = (lane >> 4) * 8 + el;
    v = (ic < 25) ? w_in[((size_t)oc * 25 + ic) * 9 + tap] : 0.f;
  } else if (e < WP_OUT) {
    int r = e - WP_W1_0;
    int layer = r / 36864;  // 0:w1b0 1:w2b0 2:w1b1 3:w2b1
    int r2 = r % 36864;
    int tap = r2 / 4096;
    int c = (r2 / 2048) & 1;
    int mt = (r2 / 512) & 3;
    int lane = (r2 / 8) & 63;
    int el = r2 & 7;
    int oc = mt * 16 + (lane & 15);
    int ic = c * 32 + (lane >> 4) * 8 + el;
    const float* src = (layer & 1) ? w2s : w1s;
    int blk = layer >> 1;
    v = src[(((size_t)blk * 64 + oc) * 64 + ic) * 9 + tap];
  } else {
    int r2 = e - WP_OUT;
    int tap = r2 / 1024;
    int c = (r2 / 512) & 1;
    int lane = (r2 / 8) & 63;
    int el = r2 & 7;
    int oc = lane & 15;
    int ic = c * 32 + (lane >> 4) * 8 + el;
    v = (oc < 9) ? w_out[((size_t)oc * 64 + ic) * 9 + tap] : 0.f;
  }
  wp[e] = __float2bfloat16(v);
}

// ---------------------------------------------------------------------------
// device helpers for the mega kernel
// ---------------------------------------------------------------------------
DEVFN void pack_held(const f32x4 (&acc)[4][4], const float* __restrict__ bias,
                     bool silu, int g, ushort4 (&held)[16]) {
#pragma unroll
  for (int mt = 0; mt < 4; ++mt) {
    const float4 b4 = *(const float4*)(bias + mt * 16 + g * 4);
#pragma unroll
    for (int nt = 0; nt < 4; ++nt) {
      float v0 = acc[mt][nt][0] + b4.x;
      float v1 = acc[mt][nt][1] + b4.y;
      float v2 = acc[mt][nt][2] + b4.z;
      float v3 = acc[mt][nt][3] + b4.w;
      if (silu) {
        v0 = v0 / (1.f + expf(-v0));
        v1 = v1 / (1.f + expf(-v1));
        v2 = v2 / (1.f + expf(-v2));
        v3 = v3 / (1.f + expf(-v3));
      }
      ushort4 s;
      s.x = f2bs(v0);
      s.y = f2bs(v1);
      s.z = f2bs(v2);
      s.w = f2bs(v3);
      held[mt * 4 + nt] = s;
    }
  }
}

// pair p (rows 2p,2p+1): inner conv loop (round-8 proven shape, 84 VGPR)
template <int CK>
DEVFN void compute_pair(const char* tile, const int (&rb)[3][2],
                        const __hip_bfloat16* __restrict__ wpf,
                        const __hip_bfloat16* hg, bool resid, int p, int lane,
                        int g, int ln, f32x4 (&acc)[4][4]) {
  if (resid) {
#pragma unroll
    for (int mt = 0; mt < 4; ++mt)
#pragma unroll
      for (int oy = 0; oy < 2; ++oy)
#pragma unroll
        for (int xh = 0; xh < 2; ++xh) {
          const int px = (2 * p + oy) * 32 + xh * 16 + ln;
          ushort4 h4 = *(const ushort4*)(hg + (size_t)px * 64 + mt * 16 + g * 4);
          f32x4 a4;
          a4[0] = bs2f(h4.x);
          a4[1] = bs2f(h4.y);
          a4[2] = bs2f(h4.z);
          a4[3] = bs2f(h4.w);
          acc[mt][oy * 2 + xh] = a4;
        }
  } else {
#pragma unroll
    for (int mt = 0; mt < 4; ++mt)
#pragma unroll
      for (int nt = 0; nt < 4; ++nt) acc[mt][nt] = (f32x4)0.f;
  }
  const int rowOff = 2 * p * SR;
#pragma unroll
  for (int c = 0; c < CK; ++c)
#pragma unroll
    for (int d = 0; d < 3; ++d) {
      bf16x8 bv[4][2];
#pragma unroll
      for (int j = 0; j < 4; ++j)
#pragma unroll
        for (int xh = 0; xh < 2; ++xh)
          bv[j][xh] = *(const bf16x8*)(tile + rowOff + j * SR + rb[d][c] +
                                       xh * 2048);
#pragma unroll
      for (int mt = 0; mt < 4; ++mt)
#pragma unroll
        for (int dyi = 0; dyi < 3; ++dyi) {
          bf16x8 av = *(const bf16x8*)(wpf +
                                       ((((dyi * 3 + d) * CK + c) * 4 + mt) *
                                            64 +
                                        lane) *
                                           8);
#pragma unroll
          for (int oy = 0; oy < 2; ++oy)
#pragma unroll
            for (int xh = 0; xh < 2; ++xh)
              acc[mt][oy * 2 + xh] = __builtin_amdgcn_mfma_f32_16x16x32_bf16(
                  av, bv[oy + dyi][xh], acc[mt][oy * 2 + xh], 0, 0, 0);
        }
    }
}

DEVFN void write_tile(char* tile, const ushort4 (&held)[16], int p, int g,
                      int ln) {
#pragma unroll
  for (int mt = 0; mt < 4; ++mt)
#pragma unroll
    for (int oy = 0; oy < 2; ++oy)
#pragma unroll
      for (int xh = 0; xh < 2; ++xh) {
        const int sx = 1 + xh * 16 + ln;
        const int addr = (2 * p + 1 + oy) * SR + sx * 128 +
                         ((mt * 32 + g * 8) ^ ((sx & 7) << 4));
        *(ushort4*)(tile + addr) = held[mt * 4 + oy * 2 + xh];
      }
}

DEVFN void write_ring(char* ring, const ushort4 (&held)[16], int g, int ln) {
#pragma unroll
  for (int mt = 0; mt < 4; ++mt)
#pragma unroll
    for (int oy = 0; oy < 2; ++oy)
#pragma unroll
      for (int xh = 0; xh < 2; ++xh) {
        const int sxr = xh * 16 + ln;
        const int addr =
            oy * 4096 + sxr * 128 + ((mt * 32 + g * 8) ^ ((sxr & 7) << 4));
        *(ushort4*)(ring + addr) = held[mt * 4 + oy * 2 + xh];
      }
}

// re-swizzled copy ring -> tile pair p (wave-3 only, 64 lanes, 128 B/lane)
DEVFN void ring_to_tile(char* tile, const char* ring, int p, int lane) {
  const int rowr = lane >> 5, pxr = lane & 31;
  const int key_r = (pxr & 7) << 4;
  const int key_t = (((pxr + 1) & 7) << 4);
  const char* rp = ring + rowr * 4096 + pxr * 128;
  char* tp = tile + (2 * p + 1 + rowr) * SR + (pxr + 1) * 128;
#pragma unroll
  for (int q = 0; q < 8; ++q) {
    int4 v = *(const int4*)(rp + ((q * 16) ^ key_r));
    *(int4*)(tp + ((q * 16) ^ key_t)) = v;
  }
}

DEVFN void store_h(__hip_bfloat16* hg, const ushort4 (&held)[16], int p, int g,
                   int ln) {
#pragma unroll
  for (int mt = 0; mt < 4; ++mt)
#pragma unroll
    for (int oy = 0; oy < 2; ++oy)
#pragma unroll
      for (int xh = 0; xh < 2; ++xh) {
        const int px = (2 * p + oy) * 32 + xh * 16 + ln;
        *(ushort4*)(hg + (size_t)px * 64 + mt * 16 + g * 4) =
            held[mt * 4 + oy * 2 + xh];
      }
}

// one in-place conv layer over the whole image with the lag-2 stagger:
// phase s computes pairs {4s+wv}; writes only pairs <= 4s-2 (never read again
// this layer). wave3 parks pairs 7 and 15 in the LDS ring (copied in later
// phases); pairs 3 and 11 ride in wave3's h0 across one phase.
template <int CK>
DEVFN void run_layer(char* tile, char* ring, const int (&rb)[3][2],
                     const __hip_bfloat16* __restrict__ wpf,
                     const float* __restrict__ bias, __hip_bfloat16* hg,
                     bool silu, bool resid, bool storeh, int wv, int lane,
                     int g, int ln) {
  ushort4 h0[16];
  f32x4 acc[4][4];
  const bool w3 = (wv == 3);

  // s=0: compute pairs 0..3 -> h0
  compute_pair<CK>(tile, rb, wpf, hg, resid, wv, lane, g, ln, acc);
  pack_held(acc, bias, silu, g, h0);
  if (storeh) store_h(hg, h0, wv, g, ln);
  __syncthreads();

  // s=1: write pairs 0..2 (wv<=2); compute 4..7 (wv3 -> ring, keeps pair 3)
  if (!w3) write_tile(tile, h0, wv, g, ln);
  compute_pair<CK>(tile, rb, wpf, hg, resid, 4 + wv, lane, g, ln, acc);
  {
    ushort4 cur[16];
    pack_held(acc, bias, silu, g, cur);
    if (storeh) store_h(hg, cur, 4 + wv, g, ln);
    if (!w3) {
#pragma unroll
      for (int i = 0; i < 16; ++i) h0[i] = cur[i];
    } else {
      write_ring(ring, cur, g, ln);
    }
  }
  __syncthreads();

  // s=2: write pairs 4..6 (wv<=2) + pair 3 (wv3's h0); compute 8..11 -> h0
  write_tile(tile, h0, w3 ? 3 : 4 + wv, g, ln);
  compute_pair<CK>(tile, rb, wpf, hg, resid, 8 + wv, lane, g, ln, acc);
  pack_held(acc, bias, silu, g, h0);
  if (storeh) store_h(hg, h0, 8 + wv, g, ln);
  __syncthreads();

  // s=3: write pairs 8..10 (wv<=2) + pair 7 (wv3 ring->tile); compute 12..15
  if (!w3) {
    write_tile(tile, h0, 8 + wv, g, ln);
  } else {
    ring_to_tile(tile, ring, 7, lane);
  }
  compute_pair<CK>(tile, rb, wpf, hg, resid, 12 + wv, lane, g, ln, acc);
  {
    ushort4 cur[16];
    pack_held(acc, bias, silu, g, cur);
    if (storeh) store_h(hg, cur, 12 + wv, g, ln);
    if (!w3) {
#pragma unroll
      for (int i = 0; i < 16; ++i) h0[i] = cur[i];
    } else {
      write_ring(ring, cur, g, ln);  // after ring_to_tile(7): same-wave order
    }
  }
  __syncthreads();

  // tail: write pairs 12..14 (wv<=2) + pair 11 (wv3 h0) + pair 15 (ring)
  if (!w3) {
    write_tile(tile, h0, 12 + wv, g, ln);
  } else {
    write_tile(tile, h0, 11, g, ln);
    ring_to_tile(tile, ring, 15, lane);
  }
  __syncthreads();
}

// ---------------------------------------------------------------------------
// mega256: one 256-thread block per image; whole refiner LDS-resident.
// 256 thr -> 256-VGPR allocator budget (the only spill-free config; rounds
// 4-11 established cap = 65536/block_threads).
// ---------------------------------------------------------------------------
__global__ __launch_bounds__(256) void mega256(
    const float* __restrict__ latents, const int* __restrict__ idx,
    const __hip_bfloat16* __restrict__ wpk, const float* __restrict__ b_in,
    const float* __restrict__ b1s, const float* __restrict__ b2s,
    const float* __restrict__ b_out, __hip_bfloat16* hglob,
    float* __restrict__ dout) {
  __shared__ __align__(16) char tile[34 * SR];  // 147,968 B
  __shared__ __align__(16) char ring[8192];     // wave-3 parking pair

  const int img = blockIdx.x;
  const int tid = threadIdx.x;
  const int lane = tid & 63, wv = tid >> 6, g = lane >> 4, ln = lane & 15;
  const int b = img >> 7, t = img & 127;

  int t0, t1;
  float ar, a;
  interp_params(idx, b, t, t0, t1, ar, a);
  const float* z0p = latents + ((size_t)b * T + t0) * C * HW;
  const float* z1p = latents + ((size_t)b * T + t1) * C * HW;
  __hip_bfloat16* hg = hglob + (size_t)img * HW * 64;

  // ---- prep: zero halo sites (full 128B), build 25-ch input in-place ----
  if (tid < 132) {
    int sy, sx;
    if (tid < 34) {
      sy = 0;
      sx = tid;
    } else if (tid < 68) {
      sy = 33;
      sx = tid - 34;
    } else {
      int r = tid - 68;
      sy = 1 + (r >> 1);
      sx = (r & 1) * 33;
    }
    int4* p4 = (int4*)(tile + sy * SR + sx * 128);
#pragma unroll
    for (int q = 0; q < 8; ++q) p4[q] = int4{0, 0, 0, 0};
  }
  {
    const ushort ab = f2bs(a);
#pragma unroll
    for (int k2 = 0; k2 < 4; ++k2) {
      const int si = tid + k2 * 256;
      const int y = si >> 5, x = si & 31;
      char* sp = tile + (y + 1) * SR + (x + 1) * 128;
      const int key = ((x + 1) & 7) << 4;
      float v0[8], v1[8];
#pragma unroll
      for (int c2 = 0; c2 < 8; ++c2) {
        v0[c2] = z0p[c2 * HW + si];
        v1[c2] = z1p[c2 * HW + si];
      }
      ushort u[8];
      int4 q;
#pragma unroll
      for (int c2 = 0; c2 < 8; ++c2)
        u[c2] = f2bs((1.f - a) * v0[c2] + a * v1[c2]);
      q.x = (int)u[0] | ((int)u[1] << 16);
      q.y = (int)u[2] | ((int)u[3] << 16);
      q.z = (int)u[4] | ((int)u[5] << 16);
      q.w = (int)u[6] | ((int)u[7] << 16);
      *(int4*)(sp + (0 ^ key)) = q;
#pragma unroll
      for (int c2 = 0; c2 < 8; ++c2) u[c2] = f2bs(v0[c2]);
      q.x = (int)u[0] | ((int)u[1] << 16);
      q.y = (int)u[2] | ((int)u[3] << 16);
      q.z = (int)u[4] | ((int)u[5] << 16);
      q.w = (int)u[6] | ((int)u[7] << 16);
      *(int4*)(sp + (16 ^ key)) = q;
#pragma unroll
      for (int c2 = 0; c2 < 8; ++c2) u[c2] = f2bs(v1[c2]);
      q.x = (int)u[0] | ((int)u[1] << 16);
      q.y = (int)u[2] | ((int)u[3] << 16);
      q.z = (int)u[4] | ((int)u[5] << 16);
      q.w = (int)u[6] | ((int)u[7] << 16);
      *(int4*)(sp + (32 ^ key)) = q;
      q.x = (int)ab;
      q.y = 0;
      q.z = 0;
      q.w = 0;
      *(int4*)(sp + (48 ^ key)) = q;
    }
  }
  __syncthreads();

  // swizzled read bases (row term added per pair)
  int rb[3][2];
#pragma unroll
  for (int d = 0; d < 3; ++d)
#pragma unroll
    for (int c = 0; c < 2; ++c)
      rb[d][c] =
          (((ln + d) * 128 + c * 64 + g * 16) ^ (((ln + d) & 7) << 4));

  // ---- L1: conv_in (25->64), silu, store h to global (residual base) ----
  run_layer<1>(tile, ring, rb, wpk + WP_IN, b_in, hg, true, false, true, wv,
               lane, g, ln);

  // ---- residual blocks: c1 = silu conv; c2 = resid conv (h from global) ----
#pragma unroll 1
  for (int blk = 0; blk < 2; ++blk) {
#pragma unroll 1
    for (int cc = 0; cc < 2; ++cc) {
      const __hip_bfloat16* wp = wpk + WP_W1_0 + (blk * 2 + cc) * 36864;
      const float* bias = cc ? (b2s + blk * 64) : (b1s + blk * 64);
      const bool silu = (cc == 0);
      const bool resid = (cc == 1);
      const bool storeh = (cc == 1) && (blk == 0);  // h2 base for rb2
      run_layer<2>(tile, ring, rb, wp, bias, hg, silu, resid, storeh, wv, lane,
                   g, ln);
    }
  }

  // ---- final conv (64->16, 9 real) + fused z_hat / conf epilogue ----
  const bool interior = (ar > 0.f) && (ar < 1.f);
  const float aa = a * (1.f - a);
  const __hip_bfloat16* wpO = wpk + WP_OUT;
#pragma unroll 1
  for (int s = 0; s < 4; ++s) {
    const int p = 4 * s + wv;
    f32x4 facc[4];
#pragma unroll
    for (int nt = 0; nt < 4; ++nt) facc[nt] = (f32x4)0.f;
    const int rowOff = 2 * p * SR;
#pragma unroll
    for (int c = 0; c < 2; ++c)
#pragma unroll
      for (int d = 0; d < 3; ++d) {
        bf16x8 bv[4][2];
#pragma unroll
        for (int j = 0; j < 4; ++j)
#pragma unroll
          for (int xh = 0; xh < 2; ++xh)
            bv[j][xh] = *(const bf16x8*)(tile + rowOff + j * SR + rb[d][c] +
                                         xh * 2048);
#pragma unroll
        for (int dyi = 0; dyi < 3; ++dyi) {
          bf16x8 av = *(const bf16x8*)(wpO +
                                       (((dyi * 3 + d) * 2 + c) * 64 + lane) *
                                           8);
#pragma unroll
          for (int oy = 0; oy < 2; ++oy)
#pragma unroll
            for (int xh = 0; xh < 2; ++xh)
              facc[oy * 2 + xh] = __builtin_amdgcn_mfma_f32_16x16x32_bf16(
                  av, bv[oy + dyi][xh], facc[oy * 2 + xh], 0, 0, 0);
        }
      }
    // epilogue: C/D frag rows = oc (g*4+r), cols = px
#pragma unroll
    for (int oy = 0; oy < 2; ++oy)
#pragma unroll
      for (int xh = 0; xh < 2; ++xh) {
        const int nt = oy * 2 + xh;
        const int px = (2 * p + oy) * 32 + xh * 16 + ln;
        if (g < 2) {
#pragma unroll
          for (int r = 0; r < 4; ++r) {
            const int c2 = g * 4 + r;
            float res = facc[nt][r] + b_out[c2];
            float v0 = z0p[c2 * HW + px], v1 = z1p[c2 * HW + px];
            float zb = (1.f - a) * v0 + a * v1;
            dout[((size_t)img * C + c2) * HW + px] = zb + aa * res;
          }
        } else if (g == 2) {
          float unc = 1.f / (1.f + expf(-(facc[nt][0] + b_out[8])));
          float conf = interior ? fminf(fmaxf(1.f - unc, 0.f), 1.f) : 1.f;
          dout[Z_SIZE + (size_t)img * HW + px] = conf;
        }
      }
  }
}

// ---------------------------------------------------------------------------
extern "C" void kernel_launch(void* const* d_in, const int* in_sizes, int n_in,
                              void* d_out, int out_size, void* d_ws,
                              size_t ws_size, hipStream_t stream) {
  const float* latents = (const float*)d_in[0];
  const int* idx = (const int*)d_in[1];
  const float* w_in = (const float*)d_in[2];
  const float* b_in = (const float*)d_in[3];
  const float* w1s = (const float*)d_in[4];
  const float* b1s = (const float*)d_in[5];
  const float* w2s = (const float*)d_in[6];
  const float* b2s = (const float*)d_in[7];
  const float* w_out = (const float*)d_in[8];
  const float* b_out = (const float*)d_in[9];
  float* dout = (float*)d_out;

  char* ws = (char*)d_ws;
  __hip_bfloat16* hglob = (__hip_bfloat16*)ws;                    // 64 MiB
  __hip_bfloat16* wpk = (__hip_bfloat16*)(ws + (size_t)67108864);  // 350 KB

  pack_weights<<<(WP_TOT + 255) / 256, 256, 0, stream>>>(w_in, w1s, w2s, w_out,
                                                         wpk);
  mega256<<<BT, 256, 0, stream>>>(latents, idx, wpk, b_in, b1s, b2s, b_out,
                                  hglob, dout);
}

// Round 13
// 317.408 us; speedup vs baseline: 2.6995x; 1.6221x over previous
//
#include <hip/hip_runtime.h>
#include <hip/hip_bf16.h>

#define DEVFN __device__ __forceinline__

typedef __attribute__((ext_vector_type(8))) short bf16x8;
typedef __attribute__((ext_vector_type(4))) float f32x4;

constexpr int T = 128, C = 8, K = 9;
constexpr int HW = 1024;   // 32x32
constexpr int BT = 512;    // B*T images
constexpr size_t Z_SIZE = (size_t)BT * C * HW;

constexpr int SR = 34 * 128;  // 4352 B per site-row (34 sites x 128 B)

// fragment-packed weights (bf16 element offsets): [tap][c][mt][lane][8]
constexpr int WP_IN = 0;        // conv_in  [9][1][4][64][8]
constexpr int WP_W1_0 = 18432;  // then w1b0,w2b0,w1b1,w2b1 each 36864
constexpr int WP_OUT = 165888;  // final [9][2][1][64][8]
constexpr int WP_TOT = 175104;

DEVFN ushort f2bs(float x) {
  __hip_bfloat16 h = __float2bfloat16(x);
  ushort u;
  __builtin_memcpy(&u, &h, 2);
  return u;
}
DEVFN float bs2f(ushort u) {
  __hip_bfloat16 h;
  __builtin_memcpy(&h, &u, 2);
  return __bfloat162float(h);
}

// idx rows sorted ascending; branchless count, no local array (rule #20).
DEVFN void interp_params(const int* __restrict__ idx, int b, int t,
                         int& t0, int& t1, float& ar, float& a) {
  const int* ib = idx + b * K;
  int cnt = 0;
#pragma unroll
  for (int k = 0; k < K; ++k) cnt += (ib[k] <= t) ? 1 : 0;
  int seg = min(max(cnt - 1, 0), K - 2);
  t0 = ib[seg];
  t1 = ib[seg + 1];
  ar = (float)(t - t0) / (float)max(t1 - t0, 1);
  a = fminf(fmaxf(ar, 0.f), 1.f);
}

// ---------------------------------------------------------------------------
__global__ __launch_bounds__(256) void pack_weights(
    const float* __restrict__ w_in, const float* __restrict__ w1s,
    const float* __restrict__ w2s, const float* __restrict__ w_out,
    __hip_bfloat16* __restrict__ wp) {
  int e = blockIdx.x * 256 + threadIdx.x;
  if (e >= WP_TOT) return;
  float v;
  if (e < WP_W1_0) {
    int tap = e / 2048;
    int r2 = e % 2048;
    int mt = r2 / 512;
    int lane = (r2 / 8) & 63;
    int el = e & 7;
    int oc = mt * 16 + (lane & 15);
    int ic = (lane >> 4) * 8 + el;
    v = (ic < 25) ? w_in[((size_t)oc * 25 + ic) * 9 + tap] : 0.f;
  } else if (e < WP_OUT) {
    int r = e - WP_W1_0;
    int layer = r / 36864;  // 0:w1b0 1:w2b0 2:w1b1 3:w2b1
    int r2 = r % 36864;
    int tap = r2 / 4096;
    int c = (r2 / 2048) & 1;
    int mt = (r2 / 512) & 3;
    int lane = (r2 / 8) & 63;
    int el = r2 & 7;
    int oc = mt * 16 + (lane & 15);
    int ic = c * 32 + (lane >> 4) * 8 + el;
    const float* src = (layer & 1) ? w2s : w1s;
    int blk = layer >> 1;
    v = src[(((size_t)blk * 64 + oc) * 64 + ic) * 9 + tap];
  } else {
    int r2 = e - WP_OUT;
    int tap = r2 / 1024;
    int c = (r2 / 512) & 1;
    int lane = (r2 / 8) & 63;
    int el = r2 & 7;
    int oc = lane & 15;
    int ic = c * 32 + (lane >> 4) * 8 + el;
    v = (oc < 9) ? w_out[((size_t)oc * 64 + ic) * 9 + tap] : 0.f;
  }
  wp[e] = __float2bfloat16(v);
}

// ---------------------------------------------------------------------------
// one in-place conv layer. 8 waves = 4 oc-quadrants (ocq) x 2 row-halves.
// Wave processes its half's 8 pairs sequentially (half 0: 0..7 bottom-up,
// half 1: 15..8 top-down). Lag-1-after stagger:
//   phase k: [compute pair p_k (reads old rows 2p-1..2p+2); capture h] B
//            [write pair p_{k-1} (rows already consumed by all readers)] B
// Half-boundary safety: half-0 pair7 reads row16 (old) at phase7; half-1
// writes rows 16,17 only at drain. half-1 pair8 reads row15 (old) at phase7;
// half-0 writes rows 14,15 only at drain. Barriers order drain after phase7.
// ---------------------------------------------------------------------------
template <int CK, bool SILU, bool RESID, bool CAPTURE>
DEVFN void layer_run(char* tile, const __hip_bfloat16* __restrict__ wpf,
                     const float* __restrict__ bias, const int (&rb)[3][2],
                     int half, int ocq, int lane, int g, int ln,
                     ushort4 (&hreg)[8][4]) {
  const float4 b4 = *(const float4*)(bias + ocq * 16 + g * 4);
  const int wboff = ocq * 32 + g * 8;
  ushort4 held[4];
  int pprev = 0;
#pragma unroll
  for (int k = 0; k < 8; ++k) {
    const int p = half ? (15 - k) : k;
    const int rowOff = 2 * p * SR;
    f32x4 acc[4];
    if (RESID) {
#pragma unroll
      for (int nt = 0; nt < 4; ++nt) {
        f32x4 a4;
        a4[0] = bs2f(hreg[k][nt].x);
        a4[1] = bs2f(hreg[k][nt].y);
        a4[2] = bs2f(hreg[k][nt].z);
        a4[3] = bs2f(hreg[k][nt].w);
        acc[nt] = a4;
      }
    } else {
#pragma unroll
      for (int nt = 0; nt < 4; ++nt) acc[nt] = (f32x4)0.f;
    }
#pragma unroll
    for (int c = 0; c < CK; ++c)
#pragma unroll
      for (int d = 0; d < 3; ++d) {
        bf16x8 bv[4][2];
#pragma unroll
        for (int j = 0; j < 4; ++j)
#pragma unroll
          for (int xh = 0; xh < 2; ++xh)
            bv[j][xh] = *(const bf16x8*)(tile + rowOff + j * SR + rb[d][c] +
                                         xh * 2048);
#pragma unroll
        for (int dyi = 0; dyi < 3; ++dyi) {
          bf16x8 av = *(const bf16x8*)(wpf +
                                       ((((dyi * 3 + d) * CK + c) * 4 + ocq) *
                                            64 +
                                        lane) *
                                           8);
#pragma unroll
          for (int oy = 0; oy < 2; ++oy)
#pragma unroll
            for (int xh = 0; xh < 2; ++xh)
              acc[oy * 2 + xh] = __builtin_amdgcn_mfma_f32_16x16x32_bf16(
                  av, bv[oy + dyi][xh], acc[oy * 2 + xh], 0, 0, 0);
        }
      }
    ushort4 cur[4];
#pragma unroll
    for (int nt = 0; nt < 4; ++nt) {
      float v0 = acc[nt][0] + b4.x;
      float v1 = acc[nt][1] + b4.y;
      float v2 = acc[nt][2] + b4.z;
      float v3 = acc[nt][3] + b4.w;
      if (SILU) {
        v0 = v0 / (1.f + expf(-v0));
        v1 = v1 / (1.f + expf(-v1));
        v2 = v2 / (1.f + expf(-v2));
        v3 = v3 / (1.f + expf(-v3));
      }
      ushort4 s;
      s.x = f2bs(v0);
      s.y = f2bs(v1);
      s.z = f2bs(v2);
      s.w = f2bs(v3);
      cur[nt] = s;
    }
    if (CAPTURE) {  // read old h at own pair rows (overwritten at phase k+1)
#pragma unroll
      for (int oy = 0; oy < 2; ++oy)
#pragma unroll
        for (int xh = 0; xh < 2; ++xh) {
          const int sx = 1 + xh * 16 + ln;
          hreg[k][oy * 2 + xh] =
              *(const ushort4*)(tile + (2 * p + 1 + oy) * SR + sx * 128 +
                                (wboff ^ ((sx & 7) << 4)));
        }
    }
    __syncthreads();
    if (k > 0) {
#pragma unroll
      for (int oy = 0; oy < 2; ++oy)
#pragma unroll
        for (int xh = 0; xh < 2; ++xh) {
          const int sx = 1 + xh * 16 + ln;
          *(ushort4*)(tile + (2 * pprev + 1 + oy) * SR + sx * 128 +
                      (wboff ^ ((sx & 7) << 4))) = held[oy * 2 + xh];
        }
    }
#pragma unroll
    for (int nt = 0; nt < 4; ++nt) held[nt] = cur[nt];
    pprev = p;
    __syncthreads();
  }
  // drain: write last pair
#pragma unroll
  for (int oy = 0; oy < 2; ++oy)
#pragma unroll
    for (int xh = 0; xh < 2; ++xh) {
      const int sx = 1 + xh * 16 + ln;
      *(ushort4*)(tile + (2 * pprev + 1 + oy) * SR + sx * 128 +
                  (wboff ^ ((sx & 7) << 4))) = held[oy * 2 + xh];
    }
  __syncthreads();
}

// ---------------------------------------------------------------------------
// megaD: one 512-thread block per image; whole refiner LDS-resident.
// 512 thr -> 128-VGPR budget; per-pair acc=16 regs (oc-split) fits.
// ---------------------------------------------------------------------------
__global__ __launch_bounds__(512) void megaD(
    const float* __restrict__ latents, const int* __restrict__ idx,
    const __hip_bfloat16* __restrict__ wpk, const float* __restrict__ b_in,
    const float* __restrict__ b1s, const float* __restrict__ b2s,
    const float* __restrict__ b_out, float* __restrict__ dout) {
  __shared__ __align__(16) char tile[34 * SR];  // 147,968 B

  const int img = blockIdx.x;
  const int tid = threadIdx.x;
  const int lane = tid & 63, wv = tid >> 6, g = lane >> 4, ln = lane & 15;
  const int ocq = wv & 3, half = wv >> 2;
  const int b = img >> 7, t = img & 127;

  int t0, t1;
  float ar, a;
  interp_params(idx, b, t, t0, t1, ar, a);
  const float* z0p = latents + ((size_t)b * T + t0) * C * HW;
  const float* z1p = latents + ((size_t)b * T + t1) * C * HW;

  // ---- prep: zero halo sites (full 128B), build 25-ch input in-place ----
  if (tid < 132) {
    int sy, sx;
    if (tid < 34) {
      sy = 0;
      sx = tid;
    } else if (tid < 68) {
      sy = 33;
      sx = tid - 34;
    } else {
      int r = tid - 68;
      sy = 1 + (r >> 1);
      sx = (r & 1) * 33;
    }
    int4* p4 = (int4*)(tile + sy * SR + sx * 128);
#pragma unroll
    for (int q = 0; q < 8; ++q) p4[q] = int4{0, 0, 0, 0};
  }
  {
    const ushort ab = f2bs(a);
#pragma unroll
    for (int k2 = 0; k2 < 2; ++k2) {
      const int si = k2 * 512 + tid;
      const int y = si >> 5, x = si & 31;
      char* sp = tile + (y + 1) * SR + (x + 1) * 128;
      const int key = ((x + 1) & 7) << 4;
      float v0[8], v1[8];
#pragma unroll
      for (int c2 = 0; c2 < 8; ++c2) {
        v0[c2] = z0p[c2 * HW + si];
        v1[c2] = z1p[c2 * HW + si];
      }
      ushort u[8];
      int4 q;
#pragma unroll
      for (int c2 = 0; c2 < 8; ++c2)
        u[c2] = f2bs((1.f - a) * v0[c2] + a * v1[c2]);
      q.x = (int)u[0] | ((int)u[1] << 16);
      q.y = (int)u[2] | ((int)u[3] << 16);
      q.z = (int)u[4] | ((int)u[5] << 16);
      q.w = (int)u[6] | ((int)u[7] << 16);
      *(int4*)(sp + (0 ^ key)) = q;
#pragma unroll
      for (int c2 = 0; c2 < 8; ++c2) u[c2] = f2bs(v0[c2]);
      q.x = (int)u[0] | ((int)u[1] << 16);
      q.y = (int)u[2] | ((int)u[3] << 16);
      q.z = (int)u[4] | ((int)u[5] << 16);
      q.w = (int)u[6] | ((int)u[7] << 16);
      *(int4*)(sp + (16 ^ key)) = q;
#pragma unroll
      for (int c2 = 0; c2 < 8; ++c2) u[c2] = f2bs(v1[c2]);
      q.x = (int)u[0] | ((int)u[1] << 16);
      q.y = (int)u[2] | ((int)u[3] << 16);
      q.z = (int)u[4] | ((int)u[5] << 16);
      q.w = (int)u[6] | ((int)u[7] << 16);
      *(int4*)(sp + (32 ^ key)) = q;
      q.x = (int)ab;
      q.y = 0;
      q.z = 0;
      q.w = 0;
      *(int4*)(sp + (48 ^ key)) = q;
    }
  }
  __syncthreads();

  // swizzled read bases (row term added per pair)
  int rb[3][2];
#pragma unroll
  for (int d = 0; d < 3; ++d)
#pragma unroll
    for (int c = 0; c < 2; ++c)
      rb[d][c] = (((ln + d) * 128 + c * 64 + g * 16) ^ (((ln + d) & 7) << 4));

  ushort4 hreg[8][4];

  // ---- L1: conv_in (25->64), silu ----
  layer_run<1, true, false, false>(tile, wpk + WP_IN, b_in, rb, half, ocq,
                                   lane, g, ln, hreg);

  // ---- residual blocks: u = silu(conv1(h)); h = h + conv2(u) ----
#pragma unroll 1
  for (int blk = 0; blk < 2; ++blk) {
    layer_run<2, true, false, true>(tile, wpk + WP_W1_0 + blk * 73728,
                                    b1s + blk * 64, rb, half, ocq, lane, g, ln,
                                    hreg);
    layer_run<2, false, true, false>(tile, wpk + WP_W1_0 + 36864 + blk * 73728,
                                     b2s + blk * 64, rb, half, ocq, lane, g,
                                     ln, hreg);
  }

  // ---- final conv (64->16, 9 real) + fused z_hat / conf epilogue ----
  const bool interior = (ar > 0.f) && (ar < 1.f);
  const float aa = a * (1.f - a);
  const __hip_bfloat16* wpO = wpk + WP_OUT;
#pragma unroll
  for (int pp = 0; pp < 2; ++pp) {
    const int p = wv + pp * 8;  // 8 waves x 2 = all 16 pairs
    const int rowOff = 2 * p * SR;
    f32x4 facc[4];
#pragma unroll
    for (int nt = 0; nt < 4; ++nt) facc[nt] = (f32x4)0.f;
#pragma unroll
    for (int c = 0; c < 2; ++c)
#pragma unroll
      for (int d = 0; d < 3; ++d) {
        bf16x8 bv[4][2];
#pragma unroll
        for (int j = 0; j < 4; ++j)
#pragma unroll
          for (int xh = 0; xh < 2; ++xh)
            bv[j][xh] = *(const bf16x8*)(tile + rowOff + j * SR + rb[d][c] +
                                         xh * 2048);
#pragma unroll
        for (int dyi = 0; dyi < 3; ++dyi) {
          bf16x8 av = *(const bf16x8*)(wpO +
                                       (((dyi * 3 + d) * 2 + c) * 64 + lane) *
                                           8);
#pragma unroll
          for (int oy = 0; oy < 2; ++oy)
#pragma unroll
            for (int xh = 0; xh < 2; ++xh)
              facc[oy * 2 + xh] = __builtin_amdgcn_mfma_f32_16x16x32_bf16(
                  av, bv[oy + dyi][xh], facc[oy * 2 + xh], 0, 0, 0);
        }
      }
    // epilogue: C/D frag rows = oc (g*4+r), cols = px (verified r12)
#pragma unroll
    for (int oy = 0; oy < 2; ++oy)
#pragma unroll
      for (int xh = 0; xh < 2; ++xh) {
        const int nt = oy * 2 + xh;
        const int px = (2 * p + oy) * 32 + xh * 16 + ln;
        if (g < 2) {
#pragma unroll
          for (int r = 0; r < 4; ++r) {
            const int c2 = g * 4 + r;
            float res = facc[nt][r] + b_out[c2];
            float v0 = z0p[c2 * HW + px], v1 = z1p[c2 * HW + px];
            float zb = (1.f - a) * v0 + a * v1;
            dout[((size_t)img * C + c2) * HW + px] = zb + aa * res;
          }
        } else if (g == 2) {
          float unc = 1.f / (1.f + expf(-(facc[nt][0] + b_out[8])));
          float conf = interior ? fminf(fmaxf(1.f - unc, 0.f), 1.f) : 1.f;
          dout[Z_SIZE + (size_t)img * HW + px] = conf;
        }
      }
  }
}

// ---------------------------------------------------------------------------
extern "C" void kernel_launch(void* const* d_in, const int* in_sizes, int n_in,
                              void* d_out, int out_size, void* d_ws,
                              size_t ws_size, hipStream_t stream) {
  const float* latents = (const float*)d_in[0];
  const int* idx = (const int*)d_in[1];
  const float* w_in = (const float*)d_in[2];
  const float* b_in = (const float*)d_in[3];
  const float* w1s = (const float*)d_in[4];
  const float* b1s = (const float*)d_in[5];
  const float* w2s = (const float*)d_in[6];
  const float* b2s = (const float*)d_in[7];
  const float* w_out = (const float*)d_in[8];
  const float* b_out = (const float*)d_in[9];
  float* dout = (float*)d_out;

  __hip_bfloat16* wpk = (__hip_bfloat16*)d_ws;  // 350,208 B

  pack_weights<<<(WP_TOT + 255) / 256, 256, 0, stream>>>(w_in, w1s, w2s, w_out,
                                                         wpk);
  megaD<<<BT, 512, 0, stream>>>(latents, idx, wpk, b_in, b1s, b2s, b_out,
                                dout);
}